// Round 21
// baseline (642.315 us; speedup 1.0000x reference)
//
#include <hip/hip_runtime.h>
#include <hip/hip_bf16.h>

typedef __bf16 bf16x8 __attribute__((ext_vector_type(8)));
typedef float f32x4 __attribute__((ext_vector_type(4)));

__device__ __forceinline__ unsigned short f2bf(float x) {
  union { float f; unsigned int u; } v; v.f = x;
  unsigned int r = (v.u + 0x7FFFu + ((v.u >> 16) & 1u)) >> 16;
  return (unsigned short)r;
}
__device__ __forceinline__ float bf2f(unsigned short u) {
  union { unsigned int u; float f; } v; v.u = ((unsigned int)u) << 16;
  return v.f;
}

// feats [N][16] f32 -> [N][16] bf16 COMPACT (row N zeroed separately = zrow)
__global__ void cvt_feats_kernel(const float* __restrict__ f, unsigned short* __restrict__ fb, int n16) {
  int t = blockIdx.x * 256 + threadIdx.x;
  if (t >= n16) return;
  fb[t] = f2bf(f[t]);
}

// Pack W[k][CI][CO] f32 into MFMA B-fragment order (CI>=32 path, conv2/conv3)
__global__ void pack_w_kernel(const float* __restrict__ W, unsigned short* __restrict__ Wp,
                              int CI, int CO, int NT, int KK) {
  int t = blockIdx.x * 256 + threadIdx.x;
  int total = 27 * NT * KK * 512;
  if (t >= total) return;
  int j = t & 7, l = (t >> 3) & 63;
  int g = t >> 9;
  int kk = g % KK; g /= KK;
  int nt = g % NT; int k = g / NT;
  int kg = kk * 32 + ((l >> 4) * 8) + j;
  int c = nt * 16 + (l & 15);
  float v = (kg < CI) ? W[((size_t)k * CI + kg) * CO + c] : 0.0f;
  Wp[t] = f2bf(v);
}

// Paired pack for conv1 (CI=16): tile g holds K-rows 0-15 = W[2g], 16-31 = W[2g+1].
__global__ void pack_w_paired_kernel(const float* __restrict__ W, unsigned short* __restrict__ Wp,
                                     int CO, int NT) {
  int t = blockIdx.x * 256 + threadIdx.x;
  int total = 14 * NT * 512;
  if (t >= total) return;
  int j = t & 7, l = (t >> 3) & 63;
  int g = t >> 9;
  int nt = g % NT; int gp = g / NT;
  int kg = ((l >> 4) * 8) + j;
  int k = 2 * gp + (kg >= 16 ? 1 : 0);
  int ci = kg & 15;
  int c = nt * 16 + (l & 15);
  float v = (k <= 26) ? W[((size_t)k * 16 + ci) * CO + c] : 0.0f;
  Wp[t] = f2bf(v);
}

// tab[k][o] = input index (scatter from pair lists; unique per (k,o) by construction)
__global__ void build_table_kernel(const int* __restrict__ pin, const int* __restrict__ pout,
                                   int P, int maxo, int* __restrict__ tab,
                                   const int* __restrict__ n_ptr, int n_cap) {
  int p = blockIdx.x * 256 + threadIdx.x;
  if (p >= P) return;
  int k = blockIdx.y;
  int n = n_cap;
  if (n_ptr) { int nv = n_ptr[0]; if (nv < n) n = nv; }
  size_t e = (size_t)k * P + p;
  int o = pout[e];
  if (o < n) tab[(size_t)k * maxo + o] = pin[e];
}

// Per-lane tab loads, UNCONDITIONAL (rows pre-clamped; k clamped but load still
// issued) -> vmcnt accounting at the barrier stays exact. PAIRED: lane's k =
// 2*step + klb; overflow (>26) forces TARR=-1 (zero row + zeroed B half).
#define LDTAB(KC_, TARR) do {                                                    \
    int _k2 = PAIRED ? (2 * (KC_) + klb) : (KC_);                                \
    int _kc = _k2 > 26 ? 26 : _k2;                                               \
    _Pragma("unroll") for (int _m = 0; _m < MT; ++_m) {                          \
      int _t = tab[(size_t)_kc * maxo + rowm[_m]];                               \
      TARR[_m] = (PAIRED && _k2 > 26) ? -1 : _t;                                 \
    }                                                                            \
  } while (0)

// Gather A fragments into AB from tab values TARR; record zero-flags ZARR;
// sets D (SKIP only). Unconditional: exactly MT*KK loads per call.
#define ISSUE_A(AB, ZARR, TARR, D) do {                                          \
    if (SKIP) {                                                                  \
      bool _anyv = (TARR[0] >= 0);                                               \
      _Pragma("unroll") for (int _m = 1; _m < MT; ++_m)                          \
        _anyv = _anyv || (TARR[_m] >= 0);                                        \
      D = (__ballot(_anyv) != 0ull);                                             \
    }                                                                            \
    _Pragma("unroll") for (int _m = 0; _m < MT; ++_m) {                          \
      ZARR[_m] = (TARR[_m] < 0);                                                 \
      const unsigned short* _s = Xb + (size_t)(TARR[_m] < 0 ? zrow : TARR[_m]) * ROWS + loff; \
      _Pragma("unroll") for (int kk = 0; kk < KK; ++kk)                          \
        AB[_m][kk] = *reinterpret_cast<const bf16x8*>(_s + kk * 32);             \
    }                                                                            \
  } while (0)

// Cooperative LDS staging of the 2 B sub-tiles (KB, KB+1) into PB.
#define STAGE_B2(KB, PB) do {                                                    \
    _Pragma("unroll") for (int _s = 0; _s < 2; ++_s) {                           \
      if ((KB) + _s <= MAXK) {                                                   \
        size_t _kb = (size_t)((KB) + _s) * (size_t)SZ;                           \
        _Pragma("unroll") for (int _j = 0; _j < PER; ++_j) {                     \
          int _c = w * PER + _j;                                                 \
          const unsigned char* _gp = WpB + _kb + (size_t)_c * 1024 + (size_t)l * 16; \
          __builtin_amdgcn_global_load_lds(                                      \
              (const __attribute__((address_space(1))) void*)_gp,                \
              (__attribute__((address_space(3))) void*)((PB) + _s * SZ + _c * 1024), 16, 0, 0); \
        }                                                                        \
      }                                                                          \
    }                                                                            \
  } while (0)

// ds_read B fragments from BCUR + MFMA on buffer AB. BNIN: transform fragments
// at CONSUME time (prefetched 2 steps ago -> no new load stalls):
// v = z ? 0 : relu(v*sc+sh). No vmem ops added -> barrier counts unchanged.
#define STEP_CORE(BCUR, AB, ZB, D) do {                                          \
    if (!SKIP || (D)) {                                                          \
      if (BNIN) {                                                                \
        _Pragma("unroll") for (int _m = 0; _m < MT; ++_m)                        \
          _Pragma("unroll") for (int kk = 0; kk < KK; ++kk) {                    \
            bf16x8 _a = AB[_m][kk];                                              \
            _Pragma("unroll") for (int _j = 0; _j < 8; ++_j) {                   \
              float _v = (float)_a[_j];                                          \
              _v = _v * scl[kk][_j] + shl[kk][_j];                               \
              _v = _v > 0.f ? _v : 0.f;                                          \
              _a[_j] = (__bf16)(ZB[_m] ? 0.f : _v);                              \
            }                                                                    \
            AB[_m][kk] = _a;                                                     \
          }                                                                      \
      }                                                                          \
      _Pragma("unroll") for (int kk = 0; kk < KK; ++kk)                          \
        _Pragma("unroll") for (int nt = 0; nt < NT; ++nt) {                      \
          bf16x8 b = *reinterpret_cast<const bf16x8*>(&(BCUR)[(nt * KK + kk) * 1024 + l * 16]); \
          _Pragma("unroll") for (int _m = 0; _m < MT; ++_m)                      \
            acc[_m][nt] = __builtin_amdgcn_mfma_f32_16x16x32_bf16(AB[_m][kk], b, acc[_m][nt], 0, 0, 0); \
        }                                                                        \
    }                                                                            \
  } while (0)

// Counted-vmcnt barrier (T3/T4): stage issued FIRST in group; exactly NWAIT
// loads issued after it; vmcnt(NWAIT) completes the stage while prefetches
// stay in flight. No vmcnt(0) drain in the main loop.
#define GROUP_BARRIER() do {                                                     \
    __builtin_amdgcn_sched_barrier(0);                                           \
    asm volatile("s_waitcnt vmcnt(%0)" :: "n"(NWAIT) : "memory");                \
    __builtin_amdgcn_sched_barrier(0);                                           \
    __builtin_amdgcn_s_barrier();                                                \
  } while (0)

// Block = 4 waves x MT*16 rows, lockstep over steps in groups of 2. B
// double-buffered in LDS; A ping-pong 2 steps ahead; tab 4 ahead; counted-vmcnt
// barriers; fused BN-stats epilogue (R20). NEW: BNIN — apply upstream BN+ReLU
// on gathered A at consume time, deleting the standalone bn_apply passes.
template<int KK, int NT, int MT, bool SKIP, bool PAIRED, bool BNIN>
__global__ __launch_bounds__(256, 4) void conv_mfma_kernel(
    const unsigned short* __restrict__ Xb, const unsigned short* __restrict__ Wp,
    const int* __restrict__ tab, int maxo, int zrow,
    const int* __restrict__ n_ptr, int n_cap,
    unsigned short* __restrict__ outb, float* __restrict__ outf,
    float* __restrict__ stats_out,
    const float* __restrict__ bn_stats, const float* __restrict__ bn_gamma,
    const float* __restrict__ bn_beta, const int* __restrict__ bn_nptr, int bn_ncap) {
  const int CO = NT * 16;
  const int ROWS = PAIRED ? 16 : KK * 32;  // shorts per X row
  const int RPW = 16 * MT;                 // rows per wave
  constexpr int PER = (KK * NT) / 4;       // 1KB staging chunks per wave per sub-tile
  constexpr int SZ = KK * NT * 1024;       // bytes per B sub-tile
  constexpr int MAXK = PAIRED ? 13 : 26;   // last step index
  constexpr int GROUPS = PAIRED ? 6 : 13;  // full 2-step groups before tail
  constexpr int NWAIT = 2 * MT * KK + 2 * MT;  // loads issued after the stage

  __shared__ __align__(16) unsigned char Blds[2][2][SZ];
  __shared__ float bs[2][64];              // fused-stats block scratch

  int bid = blockIdx.x;
  { // bijective XCD-aware swizzle (m204)
    int nwg = gridDim.x;
    int q = nwg >> 3, r = nwg & 7;
    int xcd = bid & 7, orig = bid >> 3;
    bid = (xcd < r ? xcd * (q + 1) : r * (q + 1) + (xcd - r) * q) + orig;
  }

  int w = threadIdx.x >> 6, l = threadIdx.x & 63;
  int n_rows = n_cap;
  if (n_ptr) { int nv = n_ptr[0]; if (nv < n_rows) n_rows = nv; }
  if (bid * 4 * RPW >= n_rows) return;  // block-uniform exit (before any barrier)
  int lr = l & 15, lg = l >> 4;
  int klb = lg >> 1;                    // PAIRED: which of the 2 packed k's
  int loff = PAIRED ? (lg & 1) * 8 : lg * 8;  // short offset within X row
  int wbase = bid * 4 * RPW + w * RPW;

  if (stats_out && threadIdx.x < 128)   // zero stats scratch (synced by prologue barrier)
    bs[threadIdx.x >> 6][threadIdx.x & 63] = 0.f;

  // upstream-BN coefficients for this lane's 16 channels (issued BEFORE the
  // stage -> older than it in the vmcnt FIFO -> counted barrier stays exact)
  float scl[KK][8], shl[KK][8];
  if (BNIN) {
    int bn_n = bn_nptr[0]; if (bn_n > bn_ncap) bn_n = bn_ncap;
    float inv_n = 1.f / (float)bn_n;
#pragma unroll
    for (int kk = 0; kk < KK; ++kk)
#pragma unroll
      for (int j = 0; j < 8; ++j) {
        int c = kk * 32 + lg * 8 + j;
        float m = bn_stats[c] * inv_n;
        float var = bn_stats[64 + c] * inv_n - m * m;
        float s = bn_gamma[c] * rsqrtf(var + 1e-5f);
        scl[kk][j] = s; shl[kk][j] = bn_beta[c] - m * s;
      }
  }
  __builtin_amdgcn_sched_barrier(0);

  // rows clamped (not predicated) so every load always issues -> exact counts
  int rowm[MT];
#pragma unroll
  for (int m = 0; m < MT; ++m) {
    int r = wbase + m * 16 + lr;
    rowm[m] = r < n_rows ? r : (n_rows - 1);
  }

  const unsigned char* WpB = (const unsigned char*)Wp;

  f32x4 acc[MT][NT] = {};
  bf16x8 a0[MT][KK], a1[MT][KK];
  bool z0[MT], z1[MT];
  int tE[MT], tO[MT];
  bool dE = true, dO = true;

  // ---- prologue: stage group 0 (steps 0,1); A(0),A(1); tab(2),tab(3) ----
  LDTAB(0, tE);
  LDTAB(1, tO);
  STAGE_B2(0, &Blds[0][0][0]);
  __builtin_amdgcn_sched_barrier(0);
  ISSUE_A(a0, z0, tE, dE);
  ISSUE_A(a1, z1, tO, dO);
  LDTAB(2, tE);
  LDTAB(3, tO);
  GROUP_BARRIER();

  // ---- GROUPS full groups, one counted-vmcnt barrier per group ----
#pragma unroll 1
  for (int g = 0; g < GROUPS; ++g) {
    int kb = g * 2;
    unsigned char* bc = &Blds[g & 1][0][0];
    unsigned char* bn_ = &Blds[(g + 1) & 1][0][0];
    STAGE_B2(kb + 2, bn_);
    __builtin_amdgcn_sched_barrier(0);
    STEP_CORE(bc + 0 * SZ, a0, z0, dE); ISSUE_A(a0, z0, tE, dE); LDTAB(kb + 4, tE);
    STEP_CORE(bc + 1 * SZ, a1, z1, dO); ISSUE_A(a1, z1, tO, dO); LDTAB(kb + 5, tO);
    GROUP_BARRIER();
  }
  // ---- tail: non-paired = step 26; paired = steps 12,13 ----
  {
    unsigned char* bt = &Blds[GROUPS & 1][0][0];
    STEP_CORE(bt + 0 * SZ, a0, z0, dE);
    if (PAIRED) STEP_CORE(bt + 1 * SZ, a1, z1, dO);
  }

  // ---- epilogue: write-out + (optional) fused BN-stats partials ----
  float sS[NT] = {}, sQ[NT] = {};
#pragma unroll
  for (int mt = 0; mt < MT; ++mt) {
    int r0 = wbase + mt * 16 + lg * 4;
#pragma unroll
    for (int rr = 0; rr < 4; ++rr) {
      int row = r0 + rr;
      if (row < n_rows) {
#pragma unroll
        for (int nt = 0; nt < NT; ++nt) {
          float v = acc[mt][nt][rr];
          size_t off = (size_t)row * CO + nt * 16 + lr;
          if (outf) outf[off] = v;
          else outb[off] = f2bf(v);
          sS[nt] += v; sQ[nt] += v * v;
        }
      }
    }
  }
  if (stats_out) {
#pragma unroll
    for (int nt = 0; nt < NT; ++nt) {
      sS[nt] += __shfl_xor(sS[nt], 16); sS[nt] += __shfl_xor(sS[nt], 32);
      sQ[nt] += __shfl_xor(sQ[nt], 16); sQ[nt] += __shfl_xor(sQ[nt], 32);
    }
    if (l < 16) {
#pragma unroll
      for (int nt = 0; nt < NT; ++nt) {
        atomicAdd(&bs[0][nt * 16 + lr], sS[nt]);
        atomicAdd(&bs[1][nt * 16 + lr], sQ[nt]);
      }
    }
    __syncthreads();
    if (threadIdx.x < 128) {
      int h = threadIdx.x >> 6, c = threadIdx.x & 63;
      atomicAdd(&stats_out[h * 64 + c], bs[h][c]);
    }
  }
}

extern "C" void kernel_launch(void* const* d_in, const int* in_sizes, int n_in,
                              void* d_out, int out_size, void* d_ws, size_t ws_size,
                              hipStream_t stream) {
  const float* feats  = (const float*)d_in[0];
  const float* W1     = (const float*)d_in[1];
  const float* g1     = (const float*)d_in[2];
  const float* b1     = (const float*)d_in[3];
  const float* W2     = (const float*)d_in[4];
  const float* g2     = (const float*)d_in[5];
  const float* b2     = (const float*)d_in[6];
  const float* W3     = (const float*)d_in[7];
  const int* p1_in    = (const int*)d_in[8];
  const int* p1_out   = (const int*)d_in[9];
  const int* p2_in    = (const int*)d_in[10];
  const int* p2_out   = (const int*)d_in[11];
  const int* d_n1     = (const int*)d_in[12];
  float* out = (float*)d_out;

  const int N  = in_sizes[0] / 16;     // 200000
  const int P1 = in_sizes[8] / 27;
  const int P2 = in_sizes[10] / 27;
  long KP1 = in_sizes[8];
  int n1b = (int)(KP1 < 980100 ? KP1 : 980100);   // n1 <= min(#pairs1, out-grid size)
  int maxo = n1b > N ? n1b : N;

  char* p = (char*)d_ws;
  auto alloc = [&](size_t bytes) -> char* {
    char* r = p; p += (bytes + 255) & ~(size_t)255; return r;
  };
  unsigned short* featsb = (unsigned short*)alloc((size_t)(N + 1) * 16 * 2);  // compact
  unsigned short* x1b    = (unsigned short*)alloc((size_t)(n1b + 1) * 64 * 2);
  unsigned short* x2b    = (unsigned short*)alloc((size_t)(n1b + 1) * 64 * 2);
  unsigned short* W1p    = (unsigned short*)alloc((size_t)14 * 4 * 512 * 2);  // paired
  unsigned short* W2p    = (unsigned short*)alloc((size_t)27 * 4 * 2 * 512 * 2);
  unsigned short* W3p    = (unsigned short*)alloc((size_t)27 * 2 * 2 * 512 * 2);
  int*   tab   = (int*)alloc((size_t)maxo * 27 * 4);
  float* stats = (float*)alloc(256 * 4);
  if ((size_t)(p - (char*)d_ws) > ws_size) return;  // workspace insufficient -> fail visibly

  // zero-init: feats zero-row, the two x zero-rows, BN stats
  hipMemsetAsync(featsb + (size_t)N * 16, 0, 16 * 2, stream);
  hipMemsetAsync(x1b + (size_t)n1b * 64, 0, 64 * 2, stream);
  hipMemsetAsync(x2b + (size_t)n1b * 64, 0, 64 * 2, stream);
  hipMemsetAsync(stats, 0, 256 * 4, stream);

  cvt_feats_kernel<<<(N * 16 + 255) / 256, 256, 0, stream>>>(feats, featsb, N * 16);
  pack_w_paired_kernel<<<(14 * 4 * 512 + 255) / 256, 256, 0, stream>>>(W1, W1p, 64, 4);
  pack_w_kernel<<<(27 * 4 * 2 * 512 + 255) / 256, 256, 0, stream>>>(W2, W2p, 64, 64, 4, 2);
  pack_w_kernel<<<(27 * 2 * 2 * 512 + 255) / 256, 256, 0, stream>>>(W3, W3p, 64, 32, 2, 2);

  // ---- stage 1: SparseConv3d 16->64 (PAIRED; fused BN1-stats; raw x1b) ----
  hipMemsetAsync(tab, 0xFF, (size_t)n1b * 27 * 4, stream);
  build_table_kernel<<<dim3((P1 + 255) / 256, 27), 256, 0, stream>>>(
      p1_in, p1_out, P1, n1b, tab, d_n1, n1b);
  conv_mfma_kernel<1, 4, 2, true, true, false><<<(n1b + 127) / 128, 256, 0, stream>>>(
      featsb, W1p, tab, n1b, N, d_n1, n1b, x1b, nullptr, stats,
      nullptr, nullptr, nullptr, nullptr, 0);

  // ---- stage 2: SubMConv3d 64->64 (BN1+ReLU applied on gather; fused BN2-stats) ----
  hipMemsetAsync(tab, 0xFF, (size_t)n1b * 27 * 4, stream);
  build_table_kernel<<<dim3((P2 + 255) / 256, 27), 256, 0, stream>>>(
      p2_in, p2_out, P2, n1b, tab, d_n1, n1b);
  conv_mfma_kernel<2, 4, 2, false, false, true><<<(n1b + 127) / 128, 256, 0, stream>>>(
      x1b, W2p, tab, n1b, n1b, d_n1, n1b, x2b, nullptr, stats + 128,
      stats, g1, b1, d_n1, n1b);

  // ---- stage 3: SparseInverseConv3d 64->32 (BN2+ReLU applied on gather) ----
  hipMemsetAsync(tab, 0xFF, (size_t)N * 27 * 4, stream);
  build_table_kernel<<<dim3((P1 + 255) / 256, 27), 256, 0, stream>>>(
      p1_out, p1_in, P1, N, tab, nullptr, N);
  conv_mfma_kernel<2, 2, 2, true, false, true><<<(N + 127) / 128, 256, 0, stream>>>(
      x2b, W3p, tab, N, n1b, nullptr, N, nullptr, out, nullptr,
      stats + 128, g2, b2, d_n1, n1b);
}

// Round 22
// 582.956 us; speedup vs baseline: 1.1018x; 1.1018x over previous
//
#include <hip/hip_runtime.h>
#include <hip/hip_bf16.h>

typedef __bf16 bf16x8 __attribute__((ext_vector_type(8)));
typedef float f32x4 __attribute__((ext_vector_type(4)));

__device__ __forceinline__ unsigned short f2bf(float x) {
  union { float f; unsigned int u; } v; v.f = x;
  unsigned int r = (v.u + 0x7FFFu + ((v.u >> 16) & 1u)) >> 16;
  return (unsigned short)r;
}
__device__ __forceinline__ float bf2f(unsigned short u) {
  union { unsigned int u; float f; } v; v.u = ((unsigned int)u) << 16;
  return v.f;
}

// feats [N][16] f32 -> [N][16] bf16 COMPACT (row N zeroed separately = zrow)
__global__ void cvt_feats_kernel(const float* __restrict__ f, unsigned short* __restrict__ fb, int n16) {
  int t = blockIdx.x * 256 + threadIdx.x;
  if (t >= n16) return;
  fb[t] = f2bf(f[t]);
}

// Pack W[k][CI][CO] f32 into MFMA B-fragment order (CI>=32 path, conv2/conv3)
__global__ void pack_w_kernel(const float* __restrict__ W, unsigned short* __restrict__ Wp,
                              int CI, int CO, int NT, int KK) {
  int t = blockIdx.x * 256 + threadIdx.x;
  int total = 27 * NT * KK * 512;
  if (t >= total) return;
  int j = t & 7, l = (t >> 3) & 63;
  int g = t >> 9;
  int kk = g % KK; g /= KK;
  int nt = g % NT; int k = g / NT;
  int kg = kk * 32 + ((l >> 4) * 8) + j;
  int c = nt * 16 + (l & 15);
  float v = (kg < CI) ? W[((size_t)k * CI + kg) * CO + c] : 0.0f;
  Wp[t] = f2bf(v);
}

// Paired pack for conv1 (CI=16): tile g holds K-rows 0-15 = W[2g], 16-31 = W[2g+1].
__global__ void pack_w_paired_kernel(const float* __restrict__ W, unsigned short* __restrict__ Wp,
                                     int CO, int NT) {
  int t = blockIdx.x * 256 + threadIdx.x;
  int total = 14 * NT * 512;
  if (t >= total) return;
  int j = t & 7, l = (t >> 3) & 63;
  int g = t >> 9;
  int nt = g % NT; int gp = g / NT;
  int kg = ((l >> 4) * 8) + j;
  int k = 2 * gp + (kg >= 16 ? 1 : 0);
  int ci = kg & 15;
  int c = nt * 16 + (l & 15);
  float v = (k <= 26) ? W[((size_t)k * 16 + ci) * CO + c] : 0.0f;
  Wp[t] = f2bf(v);
}

// Grid-stride tab fill: -1 for o<n across all 27 k-rows. Bounded grid (2048
// blocks) — NOT R16's 103k-block mega-grid; writes only n*27 entries instead
// of memsetting the full n_cap bound (~2x larger).
__global__ void fill_tab_kernel(int* __restrict__ tab, int maxo,
                                const int* __restrict__ n_ptr, int n_cap) {
  int n = n_cap;
  if (n_ptr) { int nv = n_ptr[0]; if (nv < n) n = nv; }
  int stride = gridDim.x * 256;
  for (int o = blockIdx.x * 256 + threadIdx.x; o < n; o += stride) {
#pragma unroll
    for (int k = 0; k < 27; ++k)
      tab[(size_t)k * maxo + o] = -1;
  }
}

// tab[k][o] = input index (scatter from pair lists; unique per (k,o) by construction)
__global__ void build_table_kernel(const int* __restrict__ pin, const int* __restrict__ pout,
                                   int P, int maxo, int* __restrict__ tab,
                                   const int* __restrict__ n_ptr, int n_cap) {
  int p = blockIdx.x * 256 + threadIdx.x;
  if (p >= P) return;
  int k = blockIdx.y;
  int n = n_cap;
  if (n_ptr) { int nv = n_ptr[0]; if (nv < n) n = nv; }
  size_t e = (size_t)k * P + p;
  int o = pout[e];
  if (o < n) tab[(size_t)k * maxo + o] = pin[e];
}

// Per-lane tab loads, UNCONDITIONAL (rows pre-clamped; k clamped but load still
// issued) -> vmcnt accounting at the barrier stays exact. PAIRED: lane's k =
// 2*step + klb; overflow (>26) forces TARR=-1 (zero row + zeroed B half).
#define LDTAB(KC_, TARR) do {                                                    \
    int _k2 = PAIRED ? (2 * (KC_) + klb) : (KC_);                                \
    int _kc = _k2 > 26 ? 26 : _k2;                                               \
    _Pragma("unroll") for (int _m = 0; _m < MT; ++_m) {                          \
      int _t = tab[(size_t)_kc * maxo + rowm[_m]];                               \
      TARR[_m] = (PAIRED && _k2 > 26) ? -1 : _t;                                 \
    }                                                                            \
  } while (0)

// Gather A fragments into AB from tab values TARR; sets D (SKIP only).
// Unconditional: exactly MT*KK loads per call (zrow fallback for invalid).
#define ISSUE_A(AB, TARR, D) do {                                                \
    if (SKIP) {                                                                  \
      bool _anyv = (TARR[0] >= 0);                                               \
      _Pragma("unroll") for (int _m = 1; _m < MT; ++_m)                          \
        _anyv = _anyv || (TARR[_m] >= 0);                                        \
      D = (__ballot(_anyv) != 0ull);                                             \
    }                                                                            \
    _Pragma("unroll") for (int _m = 0; _m < MT; ++_m) {                          \
      const unsigned short* _s = Xb + (size_t)(TARR[_m] < 0 ? zrow : TARR[_m]) * ROWS + loff; \
      _Pragma("unroll") for (int kk = 0; kk < KK; ++kk)                          \
        AB[_m][kk] = *reinterpret_cast<const bf16x8*>(_s + kk * 32);             \
    }                                                                            \
  } while (0)

// Cooperative LDS staging of the 2 B sub-tiles (KB, KB+1) into PB.
#define STAGE_B2(KB, PB) do {                                                    \
    _Pragma("unroll") for (int _s = 0; _s < 2; ++_s) {                           \
      if ((KB) + _s <= MAXK) {                                                   \
        size_t _kb = (size_t)((KB) + _s) * (size_t)SZ;                           \
        _Pragma("unroll") for (int _j = 0; _j < PER; ++_j) {                     \
          int _c = w * PER + _j;                                                 \
          const unsigned char* _gp = WpB + _kb + (size_t)_c * 1024 + (size_t)l * 16; \
          __builtin_amdgcn_global_load_lds(                                      \
              (const __attribute__((address_space(1))) void*)_gp,                \
              (__attribute__((address_space(3))) void*)((PB) + _s * SZ + _c * 1024), 16, 0, 0); \
        }                                                                        \
      }                                                                          \
    }                                                                            \
  } while (0)

// ds_read B fragments from BCUR + MFMA on buffer AB (per-wave skip if empty;
// contains NO vmcnt ops, so skipping cannot break the barrier count).
#define STEP_CORE(BCUR, AB, D) do {                                              \
    if (!SKIP || (D)) {                                                          \
      _Pragma("unroll") for (int kk = 0; kk < KK; ++kk)                          \
        _Pragma("unroll") for (int nt = 0; nt < NT; ++nt) {                      \
          bf16x8 b = *reinterpret_cast<const bf16x8*>(&(BCUR)[(nt * KK + kk) * 1024 + l * 16]); \
          _Pragma("unroll") for (int _m = 0; _m < MT; ++_m)                      \
            acc[_m][nt] = __builtin_amdgcn_mfma_f32_16x16x32_bf16(AB[_m][kk], b, acc[_m][nt], 0, 0, 0); \
        }                                                                        \
    }                                                                            \
  } while (0)

// Counted-vmcnt barrier (T3/T4): stage issued FIRST in group; exactly NWAIT
// loads issued after it; vmcnt(NWAIT) completes the stage while prefetches
// stay in flight. No vmcnt(0) drain in the main loop.
#define GROUP_BARRIER() do {                                                     \
    __builtin_amdgcn_sched_barrier(0);                                           \
    asm volatile("s_waitcnt vmcnt(%0)" :: "n"(NWAIT) : "memory");                \
    __builtin_amdgcn_sched_barrier(0);                                           \
    __builtin_amdgcn_s_barrier();                                                \
  } while (0)

// Block = 4 waves x MT*16 rows, lockstep over steps in groups of 2. B
// double-buffered in LDS via global_load_lds; A ping-pong 2 steps ahead; tab 4
// ahead; counted-vmcnt barriers. PAIRED (conv1): 2 offsets packed per K=32.
// Fused BN-stats epilogue (R20 win): per-column sum/sumsq from fp32 acc,
// deleting the standalone bn_stats passes. (R21's BN-on-gather reverted: it
// re-applied BN 27x per input row -> VALU-bound, +50 us.)
template<int KK, int NT, int MT, bool SKIP, bool PAIRED>
__global__ __launch_bounds__(256, 4) void conv_mfma_kernel(
    const unsigned short* __restrict__ Xb, const unsigned short* __restrict__ Wp,
    const int* __restrict__ tab, int maxo, int zrow,
    const int* __restrict__ n_ptr, int n_cap,
    unsigned short* __restrict__ outb, float* __restrict__ outf,
    float* __restrict__ stats_out) {
  const int CO = NT * 16;
  const int ROWS = PAIRED ? 16 : KK * 32;  // shorts per X row
  const int RPW = 16 * MT;                 // rows per wave
  constexpr int PER = (KK * NT) / 4;       // 1KB staging chunks per wave per sub-tile
  constexpr int SZ = KK * NT * 1024;       // bytes per B sub-tile
  constexpr int MAXK = PAIRED ? 13 : 26;   // last step index
  constexpr int GROUPS = PAIRED ? 6 : 13;  // full 2-step groups before tail
  constexpr int NWAIT = 2 * MT * KK + 2 * MT;  // loads issued after the stage

  __shared__ __align__(16) unsigned char Blds[2][2][SZ];
  __shared__ float bs[2][64];              // fused-stats block scratch (512B)

  int bid = blockIdx.x;
  { // bijective XCD-aware swizzle (m204)
    int nwg = gridDim.x;
    int q = nwg >> 3, r = nwg & 7;
    int xcd = bid & 7, orig = bid >> 3;
    bid = (xcd < r ? xcd * (q + 1) : r * (q + 1) + (xcd - r) * q) + orig;
  }

  int w = threadIdx.x >> 6, l = threadIdx.x & 63;
  int n_rows = n_cap;
  if (n_ptr) { int nv = n_ptr[0]; if (nv < n_rows) n_rows = nv; }
  if (bid * 4 * RPW >= n_rows) return;  // block-uniform exit (before any barrier)
  int lr = l & 15, lg = l >> 4;
  int klb = lg >> 1;                    // PAIRED: which of the 2 packed k's
  int loff = PAIRED ? (lg & 1) * 8 : lg * 8;  // short offset within X row
  int wbase = bid * 4 * RPW + w * RPW;

  if (stats_out && threadIdx.x < 128)   // zero stats scratch (synced by prologue barrier)
    bs[threadIdx.x >> 6][threadIdx.x & 63] = 0.f;

  // rows clamped (not predicated) so every load always issues -> exact counts
  int rowm[MT];
#pragma unroll
  for (int m = 0; m < MT; ++m) {
    int r = wbase + m * 16 + lr;
    rowm[m] = r < n_rows ? r : (n_rows - 1);
  }

  const unsigned char* WpB = (const unsigned char*)Wp;

  f32x4 acc[MT][NT] = {};
  bf16x8 a0[MT][KK], a1[MT][KK];
  int tE[MT], tO[MT];
  bool dE = true, dO = true;

  // ---- prologue: stage group 0 (steps 0,1); A(0),A(1); tab(2),tab(3) ----
  LDTAB(0, tE);
  LDTAB(1, tO);
  STAGE_B2(0, &Blds[0][0][0]);
  __builtin_amdgcn_sched_barrier(0);
  ISSUE_A(a0, tE, dE);
  ISSUE_A(a1, tO, dO);
  LDTAB(2, tE);
  LDTAB(3, tO);
  GROUP_BARRIER();

  // ---- GROUPS full groups, one counted-vmcnt barrier per group ----
#pragma unroll 1
  for (int g = 0; g < GROUPS; ++g) {
    int kb = g * 2;
    unsigned char* bc = &Blds[g & 1][0][0];
    unsigned char* bn = &Blds[(g + 1) & 1][0][0];
    STAGE_B2(kb + 2, bn);
    __builtin_amdgcn_sched_barrier(0);
    STEP_CORE(bc + 0 * SZ, a0, dE); ISSUE_A(a0, tE, dE); LDTAB(kb + 4, tE);
    STEP_CORE(bc + 1 * SZ, a1, dO); ISSUE_A(a1, tO, dO); LDTAB(kb + 5, tO);
    GROUP_BARRIER();
  }
  // ---- tail: non-paired = step 26; paired = steps 12,13 ----
  {
    unsigned char* bt = &Blds[GROUPS & 1][0][0];
    STEP_CORE(bt + 0 * SZ, a0, dE);
    if (PAIRED) STEP_CORE(bt + 1 * SZ, a1, dO);
  }

  // ---- epilogue: write-out + (optional) fused BN-stats partials ----
  float sS[NT] = {}, sQ[NT] = {};
#pragma unroll
  for (int mt = 0; mt < MT; ++mt) {
    int r0 = wbase + mt * 16 + lg * 4;
#pragma unroll
    for (int rr = 0; rr < 4; ++rr) {
      int row = r0 + rr;
      if (row < n_rows) {
#pragma unroll
        for (int nt = 0; nt < NT; ++nt) {
          float v = acc[mt][nt][rr];
          size_t off = (size_t)row * CO + nt * 16 + lr;
          if (outf) outf[off] = v;
          else outb[off] = f2bf(v);
          sS[nt] += v; sQ[nt] += v * v;
        }
      }
    }
  }
  if (stats_out) {
    // reduce over the 4 lg groups (stride-16 lanes share column nt*16+lr)
#pragma unroll
    for (int nt = 0; nt < NT; ++nt) {
      sS[nt] += __shfl_xor(sS[nt], 16); sS[nt] += __shfl_xor(sS[nt], 32);
      sQ[nt] += __shfl_xor(sQ[nt], 16); sQ[nt] += __shfl_xor(sQ[nt], 32);
    }
    if (l < 16) {
#pragma unroll
      for (int nt = 0; nt < NT; ++nt) {
        atomicAdd(&bs[0][nt * 16 + lr], sS[nt]);
        atomicAdd(&bs[1][nt * 16 + lr], sQ[nt]);
      }
    }
    __syncthreads();
    if (threadIdx.x < 128) {
      int h = threadIdx.x >> 6, c = threadIdx.x & 63;
      atomicAdd(&stats_out[h * 64 + c], bs[h][c]);
    }
  }
}

// BN apply + ReLU (standalone, once per element — R15-proven scalar form;
// already near HBM BW at 2048 blocks).
__global__ void bn_apply_kernel(unsigned short* __restrict__ xb,
                                const int* __restrict__ n_ptr, int n_cap,
                                const float* __restrict__ stats,
                                const float* __restrict__ gamma, const float* __restrict__ beta) {
  int c = threadIdx.x & 63, q = threadIdx.x >> 6;
  int n = n_ptr[0]; if (n > n_cap) n = n_cap;
  float inv_n = 1.f / (float)n;
  float m = stats[c] * inv_n;
  float var = stats[64 + c] * inv_n - m * m;
  float sc = gamma[c] * rsqrtf(var + 1e-5f);
  float sh = beta[c] - m * sc;
  for (int r = blockIdx.x * 4 + q; r < n; r += gridDim.x * 4) {
    size_t off = (size_t)r * 64 + c;
    float v = bf2f(xb[off]) * sc + sh;
    xb[off] = f2bf(v > 0.f ? v : 0.f);
  }
}

extern "C" void kernel_launch(void* const* d_in, const int* in_sizes, int n_in,
                              void* d_out, int out_size, void* d_ws, size_t ws_size,
                              hipStream_t stream) {
  const float* feats  = (const float*)d_in[0];
  const float* W1     = (const float*)d_in[1];
  const float* g1     = (const float*)d_in[2];
  const float* b1     = (const float*)d_in[3];
  const float* W2     = (const float*)d_in[4];
  const float* g2     = (const float*)d_in[5];
  const float* b2     = (const float*)d_in[6];
  const float* W3     = (const float*)d_in[7];
  const int* p1_in    = (const int*)d_in[8];
  const int* p1_out   = (const int*)d_in[9];
  const int* p2_in    = (const int*)d_in[10];
  const int* p2_out   = (const int*)d_in[11];
  const int* d_n1     = (const int*)d_in[12];
  float* out = (float*)d_out;

  const int N  = in_sizes[0] / 16;     // 200000
  const int P1 = in_sizes[8] / 27;
  const int P2 = in_sizes[10] / 27;
  long KP1 = in_sizes[8];
  int n1b = (int)(KP1 < 980100 ? KP1 : 980100);   // n1 <= min(#pairs1, out-grid size)
  int maxo = n1b > N ? n1b : N;

  char* p = (char*)d_ws;
  auto alloc = [&](size_t bytes) -> char* {
    char* r = p; p += (bytes + 255) & ~(size_t)255; return r;
  };
  unsigned short* featsb = (unsigned short*)alloc((size_t)(N + 1) * 16 * 2);  // compact
  unsigned short* x1b    = (unsigned short*)alloc((size_t)(n1b + 1) * 64 * 2);
  unsigned short* x2b    = (unsigned short*)alloc((size_t)(n1b + 1) * 64 * 2);
  unsigned short* W1p    = (unsigned short*)alloc((size_t)14 * 4 * 512 * 2);  // paired
  unsigned short* W2p    = (unsigned short*)alloc((size_t)27 * 4 * 2 * 512 * 2);
  unsigned short* W3p    = (unsigned short*)alloc((size_t)27 * 2 * 2 * 512 * 2);
  int*   tab   = (int*)alloc((size_t)maxo * 27 * 4);
  float* stats = (float*)alloc(256 * 4);
  if ((size_t)(p - (char*)d_ws) > ws_size) return;  // workspace insufficient -> fail visibly

  // zero-init: feats zero-row, the two x zero-rows, BN stats
  hipMemsetAsync(featsb + (size_t)N * 16, 0, 16 * 2, stream);
  hipMemsetAsync(x1b + (size_t)n1b * 64, 0, 64 * 2, stream);
  hipMemsetAsync(x2b + (size_t)n1b * 64, 0, 64 * 2, stream);
  hipMemsetAsync(stats, 0, 256 * 4, stream);

  cvt_feats_kernel<<<(N * 16 + 255) / 256, 256, 0, stream>>>(feats, featsb, N * 16);
  pack_w_paired_kernel<<<(14 * 4 * 512 + 255) / 256, 256, 0, stream>>>(W1, W1p, 64, 4);
  pack_w_kernel<<<(27 * 4 * 2 * 512 + 255) / 256, 256, 0, stream>>>(W2, W2p, 64, 64, 4, 2);
  pack_w_kernel<<<(27 * 2 * 2 * 512 + 255) / 256, 256, 0, stream>>>(W3, W3p, 64, 32, 2, 2);

  // ---- stage 1: SparseConv3d 16->64 (sparse tab, PAIRED; fused BN-stats) ----
  fill_tab_kernel<<<2048, 256, 0, stream>>>(tab, n1b, d_n1, n1b);
  build_table_kernel<<<dim3((P1 + 255) / 256, 27), 256, 0, stream>>>(
      p1_in, p1_out, P1, n1b, tab, d_n1, n1b);
  conv_mfma_kernel<1, 4, 2, true, true><<<(n1b + 127) / 128, 256, 0, stream>>>(
      featsb, W1p, tab, n1b, N, d_n1, n1b, x1b, nullptr, stats);
  bn_apply_kernel<<<2048, 256, 0, stream>>>(x1b, d_n1, n1b, stats, g1, b1);

  // ---- stage 2: SubMConv3d 64->64 (dense tab; fused BN-stats) ----
  fill_tab_kernel<<<2048, 256, 0, stream>>>(tab, n1b, d_n1, n1b);
  build_table_kernel<<<dim3((P2 + 255) / 256, 27), 256, 0, stream>>>(
      p2_in, p2_out, P2, n1b, tab, d_n1, n1b);
  conv_mfma_kernel<2, 4, 2, false, false><<<(n1b + 127) / 128, 256, 0, stream>>>(
      x1b, W2p, tab, n1b, n1b, d_n1, n1b, x2b, nullptr, stats + 128);
  bn_apply_kernel<<<2048, 256, 0, stream>>>(x2b, d_n1, n1b, stats + 128, g2, b2);

  // ---- stage 3: SparseInverseConv3d 64->32 (pairs swapped, sparse) ----
  hipMemsetAsync(tab, 0xFF, (size_t)N * 27 * 4, stream);
  build_table_kernel<<<dim3((P1 + 255) / 256, 27), 256, 0, stream>>>(
      p1_out, p1_in, P1, N, tab, nullptr, N);
  conv_mfma_kernel<2, 2, 2, true, false><<<(N + 127) / 128, 256, 0, stream>>>(
      x2b, W3p, tab, N, n1b, nullptr, N, nullptr, out, nullptr);
}

// Round 23
// 565.961 us; speedup vs baseline: 1.1349x; 1.0300x over previous
//
#include <hip/hip_runtime.h>
#include <hip/hip_bf16.h>

typedef __bf16 bf16x8 __attribute__((ext_vector_type(8)));
typedef float f32x4 __attribute__((ext_vector_type(4)));

__device__ __forceinline__ unsigned short f2bf(float x) {
  union { float f; unsigned int u; } v; v.f = x;
  unsigned int r = (v.u + 0x7FFFu + ((v.u >> 16) & 1u)) >> 16;
  return (unsigned short)r;
}
__device__ __forceinline__ float bf2f(unsigned int u16) {
  union { unsigned int u; float f; } v; v.u = u16 << 16;
  return v.f;
}

// feats [N][16] f32 -> [N][16] bf16 COMPACT (row N zeroed separately = zrow)
__global__ void cvt_feats_kernel(const float* __restrict__ f, unsigned short* __restrict__ fb, int n16) {
  int t = blockIdx.x * 256 + threadIdx.x;
  if (t >= n16) return;
  fb[t] = f2bf(f[t]);
}

// Pack W[k][CI][CO] f32 into MFMA B-fragment order (CI>=32 path, conv2/conv3)
__global__ void pack_w_kernel(const float* __restrict__ W, unsigned short* __restrict__ Wp,
                              int CI, int CO, int NT, int KK) {
  int t = blockIdx.x * 256 + threadIdx.x;
  int total = 27 * NT * KK * 512;
  if (t >= total) return;
  int j = t & 7, l = (t >> 3) & 63;
  int g = t >> 9;
  int kk = g % KK; g /= KK;
  int nt = g % NT; int k = g / NT;
  int kg = kk * 32 + ((l >> 4) * 8) + j;
  int c = nt * 16 + (l & 15);
  float v = (kg < CI) ? W[((size_t)k * CI + kg) * CO + c] : 0.0f;
  Wp[t] = f2bf(v);
}

// Paired pack for conv1 (CI=16): tile g holds K-rows 0-15 = W[2g], 16-31 = W[2g+1].
__global__ void pack_w_paired_kernel(const float* __restrict__ W, unsigned short* __restrict__ Wp,
                                     int CO, int NT) {
  int t = blockIdx.x * 256 + threadIdx.x;
  int total = 14 * NT * 512;
  if (t >= total) return;
  int j = t & 7, l = (t >> 3) & 63;
  int g = t >> 9;
  int nt = g % NT; int gp = g / NT;
  int kg = ((l >> 4) * 8) + j;
  int k = 2 * gp + (kg >= 16 ? 1 : 0);
  int ci = kg & 15;
  int c = nt * 16 + (l & 15);
  float v = (k <= 26) ? W[((size_t)k * 16 + ci) * CO + c] : 0.0f;
  Wp[t] = f2bf(v);
}

// Grid-stride tab fill: -1 for o<n across all 27 k-rows (bounded 2048-block grid).
__global__ void fill_tab_kernel(int* __restrict__ tab, int maxo,
                                const int* __restrict__ n_ptr, int n_cap) {
  int n = n_cap;
  if (n_ptr) { int nv = n_ptr[0]; if (nv < n) n = nv; }
  int stride = gridDim.x * 256;
  for (int o = blockIdx.x * 256 + threadIdx.x; o < n; o += stride) {
#pragma unroll
    for (int k = 0; k < 27; ++k)
      tab[(size_t)k * maxo + o] = -1;
  }
}

// tab[k][o] = input index (scatter from pair lists; unique per (k,o) by construction)
__global__ void build_table_kernel(const int* __restrict__ pin, const int* __restrict__ pout,
                                   int P, int maxo, int* __restrict__ tab,
                                   const int* __restrict__ n_ptr, int n_cap) {
  int p = blockIdx.x * 256 + threadIdx.x;
  if (p >= P) return;
  int k = blockIdx.y;
  int n = n_cap;
  if (n_ptr) { int nv = n_ptr[0]; if (nv < n) n = nv; }
  size_t e = (size_t)k * P + p;
  int o = pout[e];
  if (o < n) tab[(size_t)k * maxo + o] = pin[e];
}

// Per-lane tab loads, UNCONDITIONAL (rows pre-clamped; k clamped but load still
// issued) -> vmcnt accounting at the barrier stays exact. PAIRED: lane's k =
// 2*step + klb; overflow (>26) forces TARR=-1 (zero row + zeroed B half).
#define LDTAB(KC_, TARR) do {                                                    \
    int _k2 = PAIRED ? (2 * (KC_) + klb) : (KC_);                                \
    int _kc = _k2 > 26 ? 26 : _k2;                                               \
    _Pragma("unroll") for (int _m = 0; _m < MT; ++_m) {                          \
      int _t = tab[(size_t)_kc * maxo + rowm[_m]];                               \
      TARR[_m] = (PAIRED && _k2 > 26) ? -1 : _t;                                 \
    }                                                                            \
  } while (0)

// Gather A fragments into AB from tab values TARR; sets D (SKIP only).
// Unconditional: exactly MT*KK loads per call (zrow fallback for invalid).
#define ISSUE_A(AB, TARR, D) do {                                                \
    if (SKIP) {                                                                  \
      bool _anyv = (TARR[0] >= 0);                                               \
      _Pragma("unroll") for (int _m = 1; _m < MT; ++_m)                          \
        _anyv = _anyv || (TARR[_m] >= 0);                                        \
      D = (__ballot(_anyv) != 0ull);                                             \
    }                                                                            \
    _Pragma("unroll") for (int _m = 0; _m < MT; ++_m) {                          \
      const unsigned short* _s = Xb + (size_t)(TARR[_m] < 0 ? zrow : TARR[_m]) * ROWS + loff; \
      _Pragma("unroll") for (int kk = 0; kk < KK; ++kk)                          \
        AB[_m][kk] = *reinterpret_cast<const bf16x8*>(_s + kk * 32);             \
    }                                                                            \
  } while (0)

// Cooperative LDS staging of the 2 B sub-tiles (KB, KB+1) into PB.
#define STAGE_B2(KB, PB) do {                                                    \
    _Pragma("unroll") for (int _s = 0; _s < 2; ++_s) {                           \
      if ((KB) + _s <= MAXK) {                                                   \
        size_t _kb = (size_t)((KB) + _s) * (size_t)SZ;                           \
        _Pragma("unroll") for (int _j = 0; _j < PER; ++_j) {                     \
          int _c = w * PER + _j;                                                 \
          const unsigned char* _gp = WpB + _kb + (size_t)_c * 1024 + (size_t)l * 16; \
          __builtin_amdgcn_global_load_lds(                                      \
              (const __attribute__((address_space(1))) void*)_gp,                \
              (__attribute__((address_space(3))) void*)((PB) + _s * SZ + _c * 1024), 16, 0, 0); \
        }                                                                        \
      }                                                                          \
    }                                                                            \
  } while (0)

// ds_read B fragments from BCUR + MFMA on buffer AB (per-wave skip if empty;
// contains NO vmcnt ops, so skipping cannot break the barrier count).
#define STEP_CORE(BCUR, AB, D) do {                                              \
    if (!SKIP || (D)) {                                                          \
      _Pragma("unroll") for (int kk = 0; kk < KK; ++kk)                          \
        _Pragma("unroll") for (int nt = 0; nt < NT; ++nt) {                      \
          bf16x8 b = *reinterpret_cast<const bf16x8*>(&(BCUR)[(nt * KK + kk) * 1024 + l * 16]); \
          _Pragma("unroll") for (int _m = 0; _m < MT; ++_m)                      \
            acc[_m][nt] = __builtin_amdgcn_mfma_f32_16x16x32_bf16(AB[_m][kk], b, acc[_m][nt], 0, 0, 0); \
        }                                                                        \
    }                                                                            \
  } while (0)

// Counted-vmcnt barrier (T3/T4): stage issued FIRST in group; exactly NWAIT
// loads issued after it; vmcnt(NWAIT) completes the stage while prefetches
// stay in flight. No vmcnt(0) drain in the main loop.
#define GROUP_BARRIER() do {                                                     \
    __builtin_amdgcn_sched_barrier(0);                                           \
    asm volatile("s_waitcnt vmcnt(%0)" :: "n"(NWAIT) : "memory");                \
    __builtin_amdgcn_sched_barrier(0);                                           \
    __builtin_amdgcn_s_barrier();                                                \
  } while (0)

// Block = 4 waves x MT*16 rows, lockstep over steps in groups of 2. B
// double-buffered in LDS via global_load_lds; A ping-pong 2 steps ahead; tab 4
// ahead; counted-vmcnt barriers. PAIRED (conv1): 2 offsets packed per K=32.
// Fused BN-stats epilogue (R20 win).
template<int KK, int NT, int MT, bool SKIP, bool PAIRED>
__global__ __launch_bounds__(256, 4) void conv_mfma_kernel(
    const unsigned short* __restrict__ Xb, const unsigned short* __restrict__ Wp,
    const int* __restrict__ tab, int maxo, int zrow,
    const int* __restrict__ n_ptr, int n_cap,
    unsigned short* __restrict__ outb, float* __restrict__ outf,
    float* __restrict__ stats_out) {
  const int CO = NT * 16;
  const int ROWS = PAIRED ? 16 : KK * 32;  // shorts per X row
  const int RPW = 16 * MT;                 // rows per wave
  constexpr int PER = (KK * NT) / 4;       // 1KB staging chunks per wave per sub-tile
  constexpr int SZ = KK * NT * 1024;       // bytes per B sub-tile
  constexpr int MAXK = PAIRED ? 13 : 26;   // last step index
  constexpr int GROUPS = PAIRED ? 6 : 13;  // full 2-step groups before tail
  constexpr int NWAIT = 2 * MT * KK + 2 * MT;  // loads issued after the stage

  __shared__ __align__(16) unsigned char Blds[2][2][SZ];
  __shared__ float bs[2][64];              // fused-stats block scratch (512B)

  int bid = blockIdx.x;
  { // bijective XCD-aware swizzle (m204)
    int nwg = gridDim.x;
    int q = nwg >> 3, r = nwg & 7;
    int xcd = bid & 7, orig = bid >> 3;
    bid = (xcd < r ? xcd * (q + 1) : r * (q + 1) + (xcd - r) * q) + orig;
  }

  int w = threadIdx.x >> 6, l = threadIdx.x & 63;
  int n_rows = n_cap;
  if (n_ptr) { int nv = n_ptr[0]; if (nv < n_rows) n_rows = nv; }
  if (bid * 4 * RPW >= n_rows) return;  // block-uniform exit (before any barrier)
  int lr = l & 15, lg = l >> 4;
  int klb = lg >> 1;                    // PAIRED: which of the 2 packed k's
  int loff = PAIRED ? (lg & 1) * 8 : lg * 8;  // short offset within X row
  int wbase = bid * 4 * RPW + w * RPW;

  if (stats_out && threadIdx.x < 128)   // zero stats scratch (synced by prologue barrier)
    bs[threadIdx.x >> 6][threadIdx.x & 63] = 0.f;

  // rows clamped (not predicated) so every load always issues -> exact counts
  int rowm[MT];
#pragma unroll
  for (int m = 0; m < MT; ++m) {
    int r = wbase + m * 16 + lr;
    rowm[m] = r < n_rows ? r : (n_rows - 1);
  }

  const unsigned char* WpB = (const unsigned char*)Wp;

  f32x4 acc[MT][NT] = {};
  bf16x8 a0[MT][KK], a1[MT][KK];
  int tE[MT], tO[MT];
  bool dE = true, dO = true;

  // ---- prologue: stage group 0 (steps 0,1); A(0),A(1); tab(2),tab(3) ----
  LDTAB(0, tE);
  LDTAB(1, tO);
  STAGE_B2(0, &Blds[0][0][0]);
  __builtin_amdgcn_sched_barrier(0);
  ISSUE_A(a0, tE, dE);
  ISSUE_A(a1, tO, dO);
  LDTAB(2, tE);
  LDTAB(3, tO);
  GROUP_BARRIER();

  // ---- GROUPS full groups, one counted-vmcnt barrier per group ----
#pragma unroll 1
  for (int g = 0; g < GROUPS; ++g) {
    int kb = g * 2;
    unsigned char* bc = &Blds[g & 1][0][0];
    unsigned char* bn = &Blds[(g + 1) & 1][0][0];
    STAGE_B2(kb + 2, bn);
    __builtin_amdgcn_sched_barrier(0);
    STEP_CORE(bc + 0 * SZ, a0, dE); ISSUE_A(a0, tE, dE); LDTAB(kb + 4, tE);
    STEP_CORE(bc + 1 * SZ, a1, dO); ISSUE_A(a1, tO, dO); LDTAB(kb + 5, tO);
    GROUP_BARRIER();
  }
  // ---- tail: non-paired = step 26; paired = steps 12,13 ----
  {
    unsigned char* bt = &Blds[GROUPS & 1][0][0];
    STEP_CORE(bt + 0 * SZ, a0, dE);
    if (PAIRED) STEP_CORE(bt + 1 * SZ, a1, dO);
  }

  // ---- epilogue: write-out + (optional) fused BN-stats partials ----
  float sS[NT] = {}, sQ[NT] = {};
#pragma unroll
  for (int mt = 0; mt < MT; ++mt) {
    int r0 = wbase + mt * 16 + lg * 4;
#pragma unroll
    for (int rr = 0; rr < 4; ++rr) {
      int row = r0 + rr;
      if (row < n_rows) {
#pragma unroll
        for (int nt = 0; nt < NT; ++nt) {
          float v = acc[mt][nt][rr];
          size_t off = (size_t)row * CO + nt * 16 + lr;
          if (outf) outf[off] = v;
          else outb[off] = f2bf(v);
          sS[nt] += v; sQ[nt] += v * v;
        }
      }
    }
  }
  if (stats_out) {
    // reduce over the 4 lg groups (stride-16 lanes share column nt*16+lr)
#pragma unroll
    for (int nt = 0; nt < NT; ++nt) {
      sS[nt] += __shfl_xor(sS[nt], 16); sS[nt] += __shfl_xor(sS[nt], 32);
      sQ[nt] += __shfl_xor(sQ[nt], 16); sQ[nt] += __shfl_xor(sQ[nt], 32);
    }
    if (l < 16) {
#pragma unroll
      for (int nt = 0; nt < NT; ++nt) {
        atomicAdd(&bs[0][nt * 16 + lr], sS[nt]);
        atomicAdd(&bs[1][nt * 16 + lr], sQ[nt]);
      }
    }
    __syncthreads();
    if (threadIdx.x < 128) {
      int h = threadIdx.x >> 6, c = threadIdx.x & 63;
      atomicAdd(&stats_out[h * 64 + c], bs[h][c]);
    }
  }
}

// BN apply + ReLU, vectorized (uint2 = 4 bf16 channels/lane; isolated change
// vs R22 — the R16 regression is now attributed to its mega-grid fill_tab,
// this kernel passed correctness in R2/R16).
__global__ void bn_apply_kernel(unsigned short* __restrict__ xb,
                                const int* __restrict__ n_ptr, int n_cap,
                                const float* __restrict__ stats,
                                const float* __restrict__ gamma,
                                const float* __restrict__ beta) {
  int n = n_ptr[0]; if (n > n_cap) n = n_cap;
  int t = blockIdx.x * 256 + threadIdx.x;
  int cg = (t & 15) * 4;
  float inv_n = 1.f / (float)n;
  float sc[4], sh[4];
#pragma unroll
  for (int i = 0; i < 4; ++i) {
    float m = stats[cg + i] * inv_n;
    float var = stats[64 + cg + i] * inv_n - m * m;
    float s = gamma[cg + i] * rsqrtf(var + 1e-5f);
    sc[i] = s; sh[i] = beta[cg + i] - m * s;
  }
  int rstep = (gridDim.x * 256) >> 4;
  for (int r = t >> 4; r < n; r += rstep) {
    size_t off = (size_t)r * 64 + cg;
    uint2 d = *reinterpret_cast<uint2*>(xb + off);
    float v0 = bf2f(d.x & 0xffffu) * sc[0] + sh[0]; if (v0 < 0.f) v0 = 0.f;
    float v1 = bf2f(d.x >> 16)     * sc[1] + sh[1]; if (v1 < 0.f) v1 = 0.f;
    float v2 = bf2f(d.y & 0xffffu) * sc[2] + sh[2]; if (v2 < 0.f) v2 = 0.f;
    float v3 = bf2f(d.y >> 16)     * sc[3] + sh[3]; if (v3 < 0.f) v3 = 0.f;
    d.x = (unsigned int)f2bf(v0) | ((unsigned int)f2bf(v1) << 16);
    d.y = (unsigned int)f2bf(v2) | ((unsigned int)f2bf(v3) << 16);
    *reinterpret_cast<uint2*>(xb + off) = d;
  }
}

extern "C" void kernel_launch(void* const* d_in, const int* in_sizes, int n_in,
                              void* d_out, int out_size, void* d_ws, size_t ws_size,
                              hipStream_t stream) {
  const float* feats  = (const float*)d_in[0];
  const float* W1     = (const float*)d_in[1];
  const float* g1     = (const float*)d_in[2];
  const float* b1     = (const float*)d_in[3];
  const float* W2     = (const float*)d_in[4];
  const float* g2     = (const float*)d_in[5];
  const float* b2     = (const float*)d_in[6];
  const float* W3     = (const float*)d_in[7];
  const int* p1_in    = (const int*)d_in[8];
  const int* p1_out   = (const int*)d_in[9];
  const int* p2_in    = (const int*)d_in[10];
  const int* p2_out   = (const int*)d_in[11];
  const int* d_n1     = (const int*)d_in[12];
  float* out = (float*)d_out;

  const int N  = in_sizes[0] / 16;     // 200000
  const int P1 = in_sizes[8] / 27;
  const int P2 = in_sizes[10] / 27;
  long KP1 = in_sizes[8];
  int n1b = (int)(KP1 < 980100 ? KP1 : 980100);   // n1 <= min(#pairs1, out-grid size)
  int maxo = n1b > N ? n1b : N;

  char* p = (char*)d_ws;
  auto alloc = [&](size_t bytes) -> char* {
    char* r = p; p += (bytes + 255) & ~(size_t)255; return r;
  };
  unsigned short* featsb = (unsigned short*)alloc((size_t)(N + 1) * 16 * 2);  // compact
  unsigned short* x1b    = (unsigned short*)alloc((size_t)(n1b + 1) * 64 * 2);
  unsigned short* x2b    = (unsigned short*)alloc((size_t)(n1b + 1) * 64 * 2);
  unsigned short* W1p    = (unsigned short*)alloc((size_t)14 * 4 * 512 * 2);  // paired
  unsigned short* W2p    = (unsigned short*)alloc((size_t)27 * 4 * 2 * 512 * 2);
  unsigned short* W3p    = (unsigned short*)alloc((size_t)27 * 2 * 2 * 512 * 2);
  int*   tab   = (int*)alloc((size_t)maxo * 27 * 4);
  float* stats = (float*)alloc(256 * 4);
  if ((size_t)(p - (char*)d_ws) > ws_size) return;  // workspace insufficient -> fail visibly

  // zero-init: feats zero-row, the two x zero-rows, BN stats
  hipMemsetAsync(featsb + (size_t)N * 16, 0, 16 * 2, stream);
  hipMemsetAsync(x1b + (size_t)n1b * 64, 0, 64 * 2, stream);
  hipMemsetAsync(x2b + (size_t)n1b * 64, 0, 64 * 2, stream);
  hipMemsetAsync(stats, 0, 256 * 4, stream);

  cvt_feats_kernel<<<(N * 16 + 255) / 256, 256, 0, stream>>>(feats, featsb, N * 16);
  pack_w_paired_kernel<<<(14 * 4 * 512 + 255) / 256, 256, 0, stream>>>(W1, W1p, 64, 4);
  pack_w_kernel<<<(27 * 4 * 2 * 512 + 255) / 256, 256, 0, stream>>>(W2, W2p, 64, 64, 4, 2);
  pack_w_kernel<<<(27 * 2 * 2 * 512 + 255) / 256, 256, 0, stream>>>(W3, W3p, 64, 32, 2, 2);

  // ---- stage 1: SparseConv3d 16->64 (sparse tab, PAIRED; fused BN-stats) ----
  fill_tab_kernel<<<2048, 256, 0, stream>>>(tab, n1b, d_n1, n1b);
  build_table_kernel<<<dim3((P1 + 255) / 256, 27), 256, 0, stream>>>(
      p1_in, p1_out, P1, n1b, tab, d_n1, n1b);
  conv_mfma_kernel<1, 4, 2, true, true><<<(n1b + 127) / 128, 256, 0, stream>>>(
      featsb, W1p, tab, n1b, N, d_n1, n1b, x1b, nullptr, stats);
  bn_apply_kernel<<<2048, 256, 0, stream>>>(x1b, d_n1, n1b, stats, g1, b1);

  // ---- stage 2: SubMConv3d 64->64 (dense tab; fused BN-stats) ----
  fill_tab_kernel<<<2048, 256, 0, stream>>>(tab, n1b, d_n1, n1b);
  build_table_kernel<<<dim3((P2 + 255) / 256, 27), 256, 0, stream>>>(
      p2_in, p2_out, P2, n1b, tab, d_n1, n1b);
  conv_mfma_kernel<2, 4, 2, false, false><<<(n1b + 127) / 128, 256, 0, stream>>>(
      x1b, W2p, tab, n1b, n1b, d_n1, n1b, x2b, nullptr, stats + 128);
  bn_apply_kernel<<<2048, 256, 0, stream>>>(x2b, d_n1, n1b, stats + 128, g2, b2);

  // ---- stage 3: SparseInverseConv3d 64->32 (pairs swapped, sparse) ----
  hipMemsetAsync(tab, 0xFF, (size_t)N * 27 * 4, stream);
  build_table_kernel<<<dim3((P1 + 255) / 256, 27), 256, 0, stream>>>(
      p1_out, p1_in, P1, N, tab, nullptr, N);
  conv_mfma_kernel<2, 2, 2, true, false><<<(N + 127) / 128, 256, 0, stream>>>(
      x2b, W3p, tab, N, n1b, nullptr, N, nullptr, out, nullptr);
}